// Round 2
// baseline (126.231 us; speedup 1.0000x reference)
//
#include <hip/hip_runtime.h>

#define NEURONS 8192
#define INSIZE  8192
#define BATCH   2048
#define ROWS    2          // batch rows staged in LDS per block
#define TPB     1024       // 16 waves/block, 2 blocks/CU -> 32 waves/CU

using f4 = __attribute__((ext_vector_type(4))) float;
using f2 = __attribute__((ext_vector_type(2))) float;
using i4 = __attribute__((ext_vector_type(4))) int;

// ---------------------------------------------------------------------------
// Kernel 1: per-neuron softmax over 16 gate logits -> 4 affine coefficients.
// Every logic op is affine in {1, a1, a2, a1*a2}:
//   out[b,n] = C0 + C1*a1 + C2*a2 + C3*(a1*a2)
// ---------------------------------------------------------------------------
__global__ __launch_bounds__(256) void coef_kernel(const float* __restrict__ w,
                                                   f4* __restrict__ coef) {
    int n = blockIdx.x * blockDim.x + threadIdx.x;
    if (n >= NEURONS) return;

    const f4* w4 = reinterpret_cast<const f4*>(w + (size_t)n * 16);
    f4 v0 = w4[0], v1 = w4[1], v2 = w4[2], v3 = w4[3];
    float p[16] = {v0.x, v0.y, v0.z, v0.w,
                   v1.x, v1.y, v1.z, v1.w,
                   v2.x, v2.y, v2.z, v2.w,
                   v3.x, v3.y, v3.z, v3.w};

    float m = p[0];
    #pragma unroll
    for (int i = 1; i < 16; ++i) m = fmaxf(m, p[i]);
    float s = 0.f;
    #pragma unroll
    for (int i = 0; i < 16; ++i) { p[i] = __expf(p[i] - m); s += p[i]; }
    float inv = 1.f / s;

    float c0 = p[8] + p[9] + p[10] + p[11] + p[12] + p[13] + p[14] + p[15];
    float c1 = p[2] + p[3] + p[6] + p[7] - p[8] - p[9] - p[12] - p[13];
    float c2 = p[4] + p[5] + p[6] + p[7] - p[8] - p[9] - p[10] - p[11];
    float c3 = p[1] - p[2] - p[4] - 2.f * p[6] - p[7]
             + p[8] + 2.f * p[9] + p[11] + p[13] - p[14];

    f4 c; c.x = c0 * inv; c.y = c1 * inv; c.z = c2 * inv; c.w = c3 * inv;
    coef[n] = c;
}

// ---------------------------------------------------------------------------
// Kernel 2: stage ROWS x-rows in LDS (stream-once, nontemporal), then sweep
// neurons 2-at-a-time per thread with vectorized idx/coef loads and f2
// nontemporal stores. Random gathers hit LDS only.
// ---------------------------------------------------------------------------
__global__ __launch_bounds__(TPB, 8) void logic_kernel(const float* __restrict__ x,
                                                       const int* __restrict__ idx,
                                                       const f4* __restrict__ coef,
                                                       float* __restrict__ out) {
    __shared__ float xs[ROWS * INSIZE];   // 64 KiB

    const int b0 = blockIdx.x * ROWS;

    // Stage ROWS full rows of x, vectorized + nontemporal.
    const f4* xrow = reinterpret_cast<const f4*>(x + (size_t)b0 * INSIZE);
    f4* xs4 = reinterpret_cast<f4*>(xs);
    #pragma unroll
    for (int i = 0; i < ROWS * INSIZE / 4 / TPB; ++i) {     // 4 iters
        int j = threadIdx.x + i * TPB;
        xs4[j] = __builtin_nontemporal_load(&xrow[j]);
    }
    __syncthreads();

    float* out0 = out + (size_t)b0 * NEURONS;
    const i4* idx4 = reinterpret_cast<const i4*>(idx);

    #pragma unroll
    for (int k = 0; k < NEURONS / (TPB * 2); ++k) {         // 4 iters
        const int t  = threadIdx.x + k * TPB;               // pair index
        const int n  = 2 * t;                               // first neuron
        const i4 ii  = idx4[t];                             // (i0a,i0b,i1a,i1b)
        const f4 c0  = coef[n];
        const f4 c1  = coef[n + 1];
        #pragma unroll
        for (int r = 0; r < ROWS; ++r) {
            const float* xr = xs + r * INSIZE;
            const float a1 = xr[ii.x];
            const float a2 = xr[ii.y];
            const float b1 = xr[ii.z];
            const float b2 = xr[ii.w];
            f2 o;
            o.x = c0.x + c0.y * a1 + c0.z * a2 + c0.w * (a1 * a2);
            o.y = c1.x + c1.y * b1 + c1.z * b2 + c1.w * (b1 * b2);
            __builtin_nontemporal_store(o,
                reinterpret_cast<f2*>(&out0[(size_t)r * NEURONS + n]));
        }
    }
}

extern "C" void kernel_launch(void* const* d_in, const int* in_sizes, int n_in,
                              void* d_out, int out_size, void* d_ws, size_t ws_size,
                              hipStream_t stream) {
    const float* x   = (const float*)d_in[0];
    const float* w   = (const float*)d_in[1];
    const int*   idx = (const int*)d_in[2];
    float* out = (float*)d_out;
    f4* coef = (f4*)d_ws;   // 8192 * 16 B = 128 KiB scratch

    coef_kernel<<<NEURONS / 256, 256, 0, stream>>>(w, coef);
    logic_kernel<<<BATCH / ROWS, TPB, 0, stream>>>(x, idx, coef, out);
}